// Round 3
// baseline (416.830 us; speedup 1.0000x reference)
//
#include <hip/hip_runtime.h>
#include <stdint.h>

typedef unsigned int uint;
typedef unsigned short ushort;
typedef __attribute__((ext_vector_type(4))) float f32x4;
typedef __attribute__((ext_vector_type(8))) short short8;
typedef __attribute__((ext_vector_type(2))) uint uint2v;
typedef __attribute__((ext_vector_type(4))) uint uint4v;

#define GLOBAL_AS __attribute__((address_space(1)))
#define LDS_AS __attribute__((address_space(3)))

static constexpr int B_ = 2048, IN_ = 4096, OUT_ = 4096;
static constexpr int NT = 32;   // K chunks of 128 (crossbar tiles)
static constexpr int K = IN_;
static constexpr int NKT = 64;  // K-tiles of BK=64

static constexpr double kGRangeD = 1e-4 - 1e-5;
static constexpr float kGMin  = 1e-5f;
static constexpr float kGMax  = 1e-4f;
static constexpr float kGRange = (float)kGRangeD;            // 9e-5
static constexpr float kD2D   = (float)(0.01 * kGRangeD);    // D2D_STD
static constexpr float kRead  = (float)(0.02 * kGRangeD);    // READ_NOISE_STD
static constexpr float kInvGR = (float)(1.0 / kGRangeD);     // decode scale

// ---------------- init: zero the scalar slots (max_x, tile_max[32]) --------
__global__ void k_init(uint* scal) {
    if (threadIdx.x < 64) scal[threadIdx.x] = 0u;
}

// ---------------- global max|x| -------------------------------------------
__global__ void k_maxabs(const f32x4* __restrict__ x, int n4, uint* __restrict__ scal) {
    int stride = gridDim.x * blockDim.x;
    float m = 0.f;
    for (int i = blockIdx.x * blockDim.x + threadIdx.x; i < n4; i += stride) {
        f32x4 v = x[i];
        m = fmaxf(m, fmaxf(fmaxf(fabsf(v[0]), fabsf(v[1])), fmaxf(fabsf(v[2]), fabsf(v[3]))));
    }
#pragma unroll
    for (int off = 32; off; off >>= 1) m = fmaxf(m, __shfl_xor(m, off, 64));
    if ((threadIdx.x & 63) == 0) atomicMax(scal, __float_as_uint(m));
}

// ---------------- DAC quantize x -> integer codes stored as bf16 ----------
__global__ void k_quantx(const f32x4* __restrict__ x, uint4v* __restrict__ xq, int n8,
                         const uint* __restrict__ scal) {
    float mx = __uint_as_float(scal[0]);
    float s = mx / 127.0f;
    int stride = gridDim.x * blockDim.x;
    for (int i = blockIdx.x * blockDim.x + threadIdx.x; i < n8; i += stride) {
        f32x4 a = x[2 * i], b = x[2 * i + 1];
        uint r[8];
#pragma unroll
        for (int j = 0; j < 4; ++j) {
            float q0 = fminf(fmaxf(rintf(a[j] / s), -127.f), 127.f);
            float q1 = fminf(fmaxf(rintf(b[j] / s), -127.f), 127.f);
            r[j]     = __float_as_uint(q0) >> 16;  // exact: small ints fit bf16
            r[4 + j] = __float_as_uint(q1) >> 16;
        }
        uint4v o;
        o[0] = r[0] | (r[1] << 16); o[1] = r[2] | (r[3] << 16);
        o[2] = r[4] | (r[5] << 16); o[3] = r[6] | (r[7] << 16);
        xq[i] = o;
    }
}

// ---------------- effective weight (decode-folded) -> bf16 ----------------
__global__ void k_weff(const f32x4* __restrict__ W, const f32x4* __restrict__ dp,
                       const f32x4* __restrict__ dn, const f32x4* __restrict__ npz,
                       const f32x4* __restrict__ nnz, uint2v* __restrict__ wb, int n4) {
    int stride = gridDim.x * blockDim.x;
    for (int i = blockIdx.x * blockDim.x + threadIdx.x; i < n4; i += stride) {
        f32x4 w = W[i], a = dp[i], b = dn[i], c = npz[i], d = nnz[i];
        uint h[4];
#pragma unroll
        for (int j = 0; j < 4; ++j) {
            float wc = fminf(fmaxf(w[j], -1.f), 1.f);
            float gp = kGMin + fmaxf(wc, 0.f) * kGRange;
            float gn = kGMin + fmaxf(-wc, 0.f) * kGRange;
            gp = fminf(fmaxf(gp + kD2D * a[j] + kRead * c[j], 0.f), kGMax);
            gn = fminf(fmaxf(gn + kD2D * b[j] + kRead * d[j], 0.f), kGMax);
            float wv = (gp - gn) * kInvGR;
            uint u = __float_as_uint(wv);
            h[j] = (u + 0x7FFFu + ((u >> 16) & 1u)) >> 16;  // RNE to bf16
        }
        uint2v o; o[0] = h[0] | (h[1] << 16); o[1] = h[2] | (h[3] << 16);
        wb[i] = o;
    }
}

// ---------------- two-pass deep-pipelined GEMM with per-chunk ADC ---------
// BM=128 x BN=256, BK=64, 512 threads (8 waves, 2Mx4N), per-wave 64x64 out.
// 3-buffer LDS ring, prefetch distance 2 K-tiles, counted s_waitcnt vmcnt(6),
// raw s_barrier (never vmcnt(0) in steady state). XOR swizzle seg^=(row&7)
// applied on global source (linear gload_lds dest) and on ds_read address.
template <int PASS>
__global__ __launch_bounds__(512, 2) void k_gemm(const ushort* __restrict__ A,
                                                 const ushort* __restrict__ Bw,
                                                 uint* __restrict__ scal,
                                                 const float* __restrict__ bias,
                                                 float* __restrict__ out) {
    __shared__ ushort As[3][128 * 64];
    __shared__ ushort Bs[3][256 * 64];
    __shared__ uint cmax[NT];

    const int tid = threadIdx.x;            // 0..511
    const int lane = tid & 63;
    const int wave = tid >> 6;              // 0..7
    const int wr = wave >> 2, wc = wave & 3;  // 2 x 4
    const int lr = lane & 15, half = lane >> 4;
    const int lx = lr & 7;

    // XCD-aware block mapping: each XCD gets an 8(bm) x 4(bn) cluster.
    const int bid = blockIdx.x;
    const int xcd = bid & 7, slot = bid >> 3;      // 8 XCDs x 32 slots
    const int bm = ((xcd & 1) << 3) | (slot & 7);  // 0..15
    const int bn = ((xcd >> 1) << 2) | (slot >> 3);  // 0..15
    const int brow = bm * 128, bcol = bn * 256;

    if (PASS == 1 && tid < NT) cmax[tid] = 0u;

    // staging: thread -> (row = tid>>3 [+inst*64], seg = tid&7), 16B each.
    // A: 2 insts (128 rows), B: 4 insts (256 rows). Source col pre-XOR'd.
    const int srow = tid >> 3;
    const int sx8 = ((tid & 7) ^ (srow & 7)) * 8;
    const ushort* gA = A + (size_t)(brow + srow) * K + sx8;
    const ushort* gB = Bw + (size_t)(bcol + srow) * K + sx8;
    const int ldst = tid * 8;  // ushort offset of this thread's 16B slot

#define STAGE(buf, k0)                                                                   \
    do {                                                                                 \
        _Pragma("unroll")                                                                \
        for (int inst = 0; inst < 2; ++inst)                                             \
            __builtin_amdgcn_global_load_lds(                                            \
                (const GLOBAL_AS uint*)(gA + (size_t)inst * 64 * K + (k0)),              \
                (LDS_AS uint*)&As[buf][inst * 4096 + ldst], 16, 0, 0);                   \
        _Pragma("unroll")                                                                \
        for (int inst = 0; inst < 4; ++inst)                                             \
            __builtin_amdgcn_global_load_lds(                                            \
                (const GLOBAL_AS uint*)(gB + (size_t)inst * 64 * K + (k0)),              \
                (LDS_AS uint*)&Bs[buf][inst * 4096 + ldst], 16, 0, 0);                   \
    } while (0)

    // fragment row offsets (ushort units, ld=64)
    int rowA[4], rowB[4];
#pragma unroll
    for (int i = 0; i < 4; ++i) {
        rowA[i] = (wr * 64 + lr + i * 16) * 64;
        rowB[i] = (wc * 64 + lr + i * 16) * 64;
    }

    f32x4 acc[4][4], acc_o[4][4];
#pragma unroll
    for (int mi = 0; mi < 4; ++mi)
#pragma unroll
        for (int ni = 0; ni < 4; ++ni) {
            acc[mi][ni] = f32x4{0.f, 0.f, 0.f, 0.f};
            acc_o[mi][ni] = f32x4{0.f, 0.f, 0.f, 0.f};
        }

#define COMPUTE(buf)                                                                     \
    do {                                                                                 \
        _Pragma("unroll")                                                                \
        for (int s2 = 0; s2 < 2; ++s2) {                                                 \
            const int sx = ((s2 * 4 + half) ^ lx) * 8;                                   \
            short8 af[4], bf[4];                                                         \
            _Pragma("unroll")                                                            \
            for (int mi = 0; mi < 4; ++mi) af[mi] = *(const short8*)&As[buf][rowA[mi] + sx]; \
            _Pragma("unroll")                                                            \
            for (int ni = 0; ni < 4; ++ni) bf[ni] = *(const short8*)&Bs[buf][rowB[ni] + sx]; \
            __builtin_amdgcn_s_setprio(1);                                               \
            _Pragma("unroll")                                                            \
            for (int mi = 0; mi < 4; ++mi)                                               \
                _Pragma("unroll")                                                        \
                for (int ni = 0; ni < 4; ++ni)                                           \
                    acc[mi][ni] = __builtin_amdgcn_mfma_f32_16x16x32_bf16(               \
                        af[mi], bf[ni], acc[mi][ni], 0, 0, 0);                           \
            __builtin_amdgcn_s_setprio(0);                                               \
        }                                                                                \
    } while (0)

    // prologue: stage K-tiles 0 and 1; wait for tile 0 only (6 newest allowed).
    STAGE(0, 0);
    STAGE(1, 64);
    asm volatile("s_waitcnt vmcnt(6)" ::: "memory");
    asm volatile("s_waitcnt lgkmcnt(0)" ::: "memory");
    __builtin_amdgcn_sched_barrier(0);
    __builtin_amdgcn_s_barrier();

    int cur = 0;
    for (int kt = 0; kt < NKT; ++kt) {
        int stg = cur + 2; if (stg >= 3) stg -= 3;
        if (kt + 2 < NKT) STAGE(stg, (kt + 2) * 64);

        COMPUTE(cur);

        if (kt & 1) {
            const int t = kt >> 1;
            if (PASS == 1) {
                float m = 0.f;
#pragma unroll
                for (int mi = 0; mi < 4; ++mi)
#pragma unroll
                    for (int ni = 0; ni < 4; ++ni) {
                        f32x4 v = acc[mi][ni];
                        m = fmaxf(m, fmaxf(fmaxf(fabsf(v[0]), fabsf(v[1])),
                                           fmaxf(fabsf(v[2]), fabsf(v[3]))));
                    }
#pragma unroll
                for (int off = 32; off; off >>= 1) m = fmaxf(m, __shfl_xor(m, off, 64));
                if (lane == 0) atomicMax(&cmax[t], __float_as_uint(m));
            } else {
                float mt = __uint_as_float(scal[1 + t]);
                float stp = mt / 127.0f;
                float inv = mt > 0.f ? 127.0f / mt : 0.f;
#pragma unroll
                for (int mi = 0; mi < 4; ++mi)
#pragma unroll
                    for (int ni = 0; ni < 4; ++ni)
#pragma unroll
                        for (int e = 0; e < 4; ++e)
                            acc_o[mi][ni][e] =
                                fmaf(rintf(acc[mi][ni][e] * inv), stp, acc_o[mi][ni][e]);
            }
#pragma unroll
            for (int mi = 0; mi < 4; ++mi)
#pragma unroll
                for (int ni = 0; ni < 4; ++ni) acc[mi][ni] = f32x4{0.f, 0.f, 0.f, 0.f};
        }

        if (kt < NKT - 1) {
            if (kt < NKT - 3) asm volatile("s_waitcnt vmcnt(6)" ::: "memory");
            else              asm volatile("s_waitcnt vmcnt(0)" ::: "memory");
            __builtin_amdgcn_sched_barrier(0);
            __builtin_amdgcn_s_barrier();
        }
        cur = cur + 1; if (cur >= 3) cur -= 3;
    }

    if (PASS == 1) {
        __syncthreads();
        if (tid < NT) atomicMax(&scal[1 + tid], cmax[tid]);
    } else {
        float sxq = __uint_as_float(scal[0]) / 127.0f;
#pragma unroll
        for (int mi = 0; mi < 4; ++mi)
#pragma unroll
            for (int ni = 0; ni < 4; ++ni) {
                int gr = brow + wr * 64 + mi * 16 + half * 4;
                int gc = bcol + wc * 64 + ni * 16 + lr;
                float bv = bias[gc];
#pragma unroll
                for (int e = 0; e < 4; ++e)
                    out[(size_t)(gr + e) * OUT_ + gc] = fmaf(acc_o[mi][ni][e], sxq, bv);
            }
    }
#undef STAGE
#undef COMPUTE
}

extern "C" void kernel_launch(void* const* d_in, const int* in_sizes, int n_in,
                              void* d_out, int out_size, void* d_ws, size_t ws_size,
                              hipStream_t stream) {
    (void)in_sizes; (void)n_in; (void)out_size;
    const float* x   = (const float*)d_in[0];
    const float* W   = (const float*)d_in[1];
    const float* bias= (const float*)d_in[2];
    const float* dp  = (const float*)d_in[3];
    const float* dn  = (const float*)d_in[4];
    const float* npz = (const float*)d_in[5];
    const float* nnz = (const float*)d_in[6];
    float* out = (float*)d_out;

    uint* scal = (uint*)d_ws;
    ushort* xq = (ushort*)((char*)d_ws + 256);
    ushort* wb = (ushort*)((char*)d_ws + 256 + (size_t)B_ * IN_ * 2);
    if (ws_size < 256 + (size_t)B_ * IN_ * 2 + (size_t)OUT_ * IN_ * 2) return;

    k_init<<<1, 64, 0, stream>>>(scal);
    k_maxabs<<<2048, 256, 0, stream>>>((const f32x4*)x, B_ * IN_ / 4, scal);
    k_quantx<<<2048, 256, 0, stream>>>((const f32x4*)x, (uint4v*)xq, B_ * IN_ / 8, scal);
    k_weff<<<2048, 256, 0, stream>>>((const f32x4*)W, (const f32x4*)dp, (const f32x4*)dn,
                                     (const f32x4*)npz, (const f32x4*)nnz,
                                     (uint2v*)wb, OUT_ * IN_ / 4);
    k_gemm<1><<<256, 512, 0, stream>>>(xq, wb, scal, bias, out);
    k_gemm<2><<<256, 512, 0, stream>>>(xq, wb, scal, bias, out);
}

// Round 6
// 380.920 us; speedup vs baseline: 1.0943x; 1.0943x over previous
//
#include <hip/hip_runtime.h>
#include <stdint.h>

typedef unsigned int uint;
typedef unsigned short ushort;
typedef __attribute__((ext_vector_type(4))) float f32x4;
typedef __attribute__((ext_vector_type(8))) short short8;
typedef __attribute__((ext_vector_type(2))) uint uint2v;
typedef __attribute__((ext_vector_type(4))) uint uint4v;

#define GLOBAL_AS __attribute__((address_space(1)))
#define LDS_AS __attribute__((address_space(3)))

static constexpr int B_ = 2048, IN_ = 4096, OUT_ = 4096;
static constexpr int NT = 32;   // K chunks of 128 (crossbar tiles)
static constexpr int K = IN_;
static constexpr int NKT = 64;  // K-tiles of BK=64

static constexpr double kGRangeD = 1e-4 - 1e-5;
static constexpr float kGMin  = 1e-5f;
static constexpr float kGMax  = 1e-4f;
static constexpr float kGRange = (float)kGRangeD;            // 9e-5
static constexpr float kD2D   = (float)(0.01 * kGRangeD);    // D2D_STD
static constexpr float kRead  = (float)(0.02 * kGRangeD);    // READ_NOISE_STD
static constexpr float kInvGR = (float)(1.0 / kGRangeD);     // decode scale

// ---------------- init: zero the scalar slots (max_x, tile_max[32]) --------
__global__ void k_init(uint* scal) {
    if (threadIdx.x < 64) scal[threadIdx.x] = 0u;
}

// ---------------- global max|x| -------------------------------------------
__global__ void k_maxabs(const f32x4* __restrict__ x, int n4, uint* __restrict__ scal) {
    int stride = gridDim.x * blockDim.x;
    float m = 0.f;
    for (int i = blockIdx.x * blockDim.x + threadIdx.x; i < n4; i += stride) {
        f32x4 v = x[i];
        m = fmaxf(m, fmaxf(fmaxf(fabsf(v[0]), fabsf(v[1])), fmaxf(fabsf(v[2]), fabsf(v[3]))));
    }
#pragma unroll
    for (int off = 32; off; off >>= 1) m = fmaxf(m, __shfl_xor(m, off, 64));
    if ((threadIdx.x & 63) == 0) atomicMax(scal, __float_as_uint(m));
}

// ---------------- DAC quantize x -> integer codes stored as bf16 ----------
__global__ void k_quantx(const f32x4* __restrict__ x, uint4v* __restrict__ xq, int n8,
                         const uint* __restrict__ scal) {
    float mx = __uint_as_float(scal[0]);
    float s = mx / 127.0f;
    int stride = gridDim.x * blockDim.x;
    for (int i = blockIdx.x * blockDim.x + threadIdx.x; i < n8; i += stride) {
        f32x4 a = x[2 * i], b = x[2 * i + 1];
        uint r[8];
#pragma unroll
        for (int j = 0; j < 4; ++j) {
            float q0 = fminf(fmaxf(rintf(a[j] / s), -127.f), 127.f);
            float q1 = fminf(fmaxf(rintf(b[j] / s), -127.f), 127.f);
            r[j]     = __float_as_uint(q0) >> 16;  // exact: small ints fit bf16
            r[4 + j] = __float_as_uint(q1) >> 16;
        }
        uint4v o;
        o[0] = r[0] | (r[1] << 16); o[1] = r[2] | (r[3] << 16);
        o[2] = r[4] | (r[5] << 16); o[3] = r[6] | (r[7] << 16);
        xq[i] = o;
    }
}

// ---------------- effective weight (decode-folded) -> bf16 ----------------
__global__ void k_weff(const f32x4* __restrict__ W, const f32x4* __restrict__ dp,
                       const f32x4* __restrict__ dn, const f32x4* __restrict__ npz,
                       const f32x4* __restrict__ nnz, uint2v* __restrict__ wb, int n4) {
    int stride = gridDim.x * blockDim.x;
    for (int i = blockIdx.x * blockDim.x + threadIdx.x; i < n4; i += stride) {
        f32x4 w = W[i], a = dp[i], b = dn[i], c = npz[i], d = nnz[i];
        uint h[4];
#pragma unroll
        for (int j = 0; j < 4; ++j) {
            float wc = fminf(fmaxf(w[j], -1.f), 1.f);
            float gp = kGMin + fmaxf(wc, 0.f) * kGRange;
            float gn = kGMin + fmaxf(-wc, 0.f) * kGRange;
            gp = fminf(fmaxf(gp + kD2D * a[j] + kRead * c[j], 0.f), kGMax);
            gn = fminf(fmaxf(gn + kD2D * b[j] + kRead * d[j], 0.f), kGMax);
            float wv = (gp - gn) * kInvGR;
            uint u = __float_as_uint(wv);
            h[j] = (u + 0x7FFFu + ((u >> 16) & 1u)) >> 16;  // RNE to bf16
        }
        uint2v o; o[0] = h[0] | (h[1] << 16); o[1] = h[2] | (h[3] << 16);
        wb[i] = o;
    }
}

// ---------------- two-pass phase-interleaved GEMM with per-chunk ADC ------
// BM=128 x BN=256, BK=64, 512 threads (8 waves, 2Mx4N), per-wave 64x64 out.
// 3-buffer LDS ring, distance-2 prefetch, counted vmcnt(6) once per K-tile.
// Each K-tile = 2 template-phases:
//   {8x ds_read_b128 | 3x global_load_lds} -> s_barrier -> lgkmcnt(0) ->
//   setprio(1) 16x MFMA setprio(0) -> TAIL() -> s_barrier
// XOR swizzle seg^=(row&7) on global source (linear gload dest) + ds_read.
template <int PASS>
__global__ __launch_bounds__(512, 2) void k_gemm(const ushort* __restrict__ A,
                                                 const ushort* __restrict__ Bw,
                                                 uint* __restrict__ scal,
                                                 const float* __restrict__ bias,
                                                 float* __restrict__ out) {
    __shared__ ushort As[3][128 * 64];
    __shared__ ushort Bs[3][256 * 64];
    __shared__ uint cmax[NT];

    const int tid = threadIdx.x;            // 0..511
    const int lane = tid & 63;
    const int wave = tid >> 6;              // 0..7
    const int wr = wave >> 2, wc = wave & 3;  // 2 x 4
    const int lr = lane & 15, half = lane >> 4;
    const int lx = lr & 7;

    // XCD-aware block mapping: each XCD gets an 8(bm) x 4(bn) cluster.
    const int bid = blockIdx.x;
    const int xcd = bid & 7, slot = bid >> 3;        // 8 XCDs x 32 slots
    const int bm = ((xcd & 1) << 3) | (slot & 7);    // 0..15
    const int bn = ((xcd >> 1) << 2) | (slot >> 3);  // 0..15
    const int brow = bm * 128, bcol = bn * 256;

    if (PASS == 1 && tid < NT) cmax[tid] = 0u;

    // staging: thread -> (row = tid>>3 [+inst*64], seg = tid&7), 16B each.
    const int srow = tid >> 3;
    const int sx8 = ((tid & 7) ^ (srow & 7)) * 8;
    const ushort* gA = A + (size_t)(brow + srow) * K + sx8;
    const ushort* gB = Bw + (size_t)(bcol + srow) * K + sx8;
    const int ldst = tid * 8;  // ushort offset of this thread's 16B slot

#define GLOAD(src, dst) \
    __builtin_amdgcn_global_load_lds((const GLOBAL_AS uint*)(src), (LDS_AS uint*)(dst), 16, 0, 0)

    // part 0: A rows 0-127 (2 insts) + B rows 0-63; part 1: B rows 64-255.
#define STAGE_P(buf, k0, part)                                                           \
    do {                                                                                 \
        if ((part) == 0) {                                                               \
            GLOAD(gA + (k0), &As[buf][ldst]);                                            \
            GLOAD(gA + (size_t)64 * K + (k0), &As[buf][4096 + ldst]);                    \
            GLOAD(gB + (k0), &Bs[buf][ldst]);                                            \
        } else {                                                                         \
            GLOAD(gB + (size_t)64 * K + (k0), &Bs[buf][4096 + ldst]);                    \
            GLOAD(gB + (size_t)128 * K + (k0), &Bs[buf][8192 + ldst]);                   \
            GLOAD(gB + (size_t)192 * K + (k0), &Bs[buf][12288 + ldst]);                  \
        }                                                                                \
    } while (0)

    // fragment row offsets (ushort units, ld=64)
    int rowA[4], rowB[4];
#pragma unroll
    for (int i = 0; i < 4; ++i) {
        rowA[i] = (wr * 64 + lr + i * 16) * 64;
        rowB[i] = (wc * 64 + lr + i * 16) * 64;
    }

    f32x4 acc[4][4], acc_o[4][4];
#pragma unroll
    for (int mi = 0; mi < 4; ++mi)
#pragma unroll
        for (int ni = 0; ni < 4; ++ni) {
            acc[mi][ni] = f32x4{0.f, 0.f, 0.f, 0.f};
            acc_o[mi][ni] = f32x4{0.f, 0.f, 0.f, 0.f};
        }

    // one template-phase; TAIL is a named lambda invoked before the closing
    // barrier (defined outside the macro call so #pragma is legal inside it).
#define PHASE(buf, s2, stg, k2, do_stage, part, TAIL)                                    \
    do {                                                                                 \
        const int sx = (((s2) * 4 + half) ^ lx) * 8;                                     \
        short8 af[4], bf[4];                                                             \
        _Pragma("unroll")                                                                \
        for (int mi = 0; mi < 4; ++mi) af[mi] = *(const short8*)&As[buf][rowA[mi] + sx]; \
        _Pragma("unroll")                                                                \
        for (int ni = 0; ni < 4; ++ni) bf[ni] = *(const short8*)&Bs[buf][rowB[ni] + sx]; \
        if (do_stage) STAGE_P(stg, k2, part);                                            \
        __builtin_amdgcn_s_barrier();                                                    \
        asm volatile("s_waitcnt lgkmcnt(0)" ::: "memory");                               \
        __builtin_amdgcn_sched_barrier(0);                                               \
        __builtin_amdgcn_s_setprio(1);                                                   \
        _Pragma("unroll")                                                                \
        for (int mi = 0; mi < 4; ++mi)                                                   \
            _Pragma("unroll")                                                            \
            for (int ni = 0; ni < 4; ++ni)                                               \
                acc[mi][ni] = __builtin_amdgcn_mfma_f32_16x16x32_bf16(af[mi], bf[ni],    \
                                                                      acc[mi][ni], 0, 0, 0); \
        __builtin_amdgcn_s_setprio(0);                                                   \
        TAIL();                                                                          \
        __builtin_amdgcn_s_barrier();                                                    \
    } while (0)

    // prologue: stage K-tiles 0 and 1; wait for tile 0 only.
    STAGE_P(0, 0, 0);
    STAGE_P(0, 0, 1);
    STAGE_P(1, 64, 0);
    STAGE_P(1, 64, 1);
    asm volatile("s_waitcnt vmcnt(6)" ::: "memory");
    __builtin_amdgcn_sched_barrier(0);
    __builtin_amdgcn_s_barrier();

    int cur = 0;
    for (int kt = 0; kt < NKT; ++kt) {
        int stg = cur + 2; if (stg >= 3) stg -= 3;
        const bool do_stage = (kt + 2 < NKT);
        const int k2 = (kt + 2) * 64;

        auto tail_none = [&]() {};

        auto tail_adc = [&]() {
            if (kt & 1) {
                const int t = kt >> 1;
                if (PASS == 1) {
                    float m = 0.f;
#pragma unroll
                    for (int mi = 0; mi < 4; ++mi)
#pragma unroll
                        for (int ni = 0; ni < 4; ++ni) {
                            f32x4 v = acc[mi][ni];
                            m = fmaxf(m, fmaxf(fmaxf(fabsf(v[0]), fabsf(v[1])),
                                               fmaxf(fabsf(v[2]), fabsf(v[3]))));
                        }
#pragma unroll
                    for (int off = 32; off; off >>= 1) m = fmaxf(m, __shfl_xor(m, off, 64));
                    if (lane == 0) atomicMax(&cmax[t], __float_as_uint(m));
                } else {
                    float mt = __uint_as_float(scal[1 + t]);
                    float stp = mt / 127.0f;
                    float inv = mt > 0.f ? 127.0f / mt : 0.f;
#pragma unroll
                    for (int mi = 0; mi < 4; ++mi)
#pragma unroll
                        for (int ni = 0; ni < 4; ++ni)
#pragma unroll
                            for (int e = 0; e < 4; ++e)
                                acc_o[mi][ni][e] =
                                    fmaf(rintf(acc[mi][ni][e] * inv), stp, acc_o[mi][ni][e]);
                }
#pragma unroll
                for (int mi = 0; mi < 4; ++mi)
#pragma unroll
                    for (int ni = 0; ni < 4; ++ni) acc[mi][ni] = f32x4{0.f, 0.f, 0.f, 0.f};
            }
            if (kt < NKT - 1) {
                if (kt < NKT - 3) { asm volatile("s_waitcnt vmcnt(6)" ::: "memory"); }
                else              { asm volatile("s_waitcnt vmcnt(0)" ::: "memory"); }
                __builtin_amdgcn_sched_barrier(0);
            }
        };

        PHASE(cur, 0, stg, k2, do_stage, 0, tail_none);
        PHASE(cur, 1, stg, k2, do_stage, 1, tail_adc);

        cur = cur + 1; if (cur >= 3) cur -= 3;
    }

    if (PASS == 1) {
        __syncthreads();
        if (tid < NT) atomicMax(&scal[1 + tid], cmax[tid]);
    } else {
        float sxq = __uint_as_float(scal[0]) / 127.0f;
#pragma unroll
        for (int mi = 0; mi < 4; ++mi)
#pragma unroll
            for (int ni = 0; ni < 4; ++ni) {
                int gr = brow + wr * 64 + mi * 16 + half * 4;
                int gc = bcol + wc * 64 + ni * 16 + lr;
                float bv = bias[gc];
#pragma unroll
                for (int e = 0; e < 4; ++e)
                    out[(size_t)(gr + e) * OUT_ + gc] = fmaf(acc_o[mi][ni][e], sxq, bv);
            }
    }
#undef PHASE
#undef STAGE_P
#undef GLOAD
}

extern "C" void kernel_launch(void* const* d_in, const int* in_sizes, int n_in,
                              void* d_out, int out_size, void* d_ws, size_t ws_size,
                              hipStream_t stream) {
    (void)in_sizes; (void)n_in; (void)out_size;
    const float* x   = (const float*)d_in[0];
    const float* W   = (const float*)d_in[1];
    const float* bias= (const float*)d_in[2];
    const float* dp  = (const float*)d_in[3];
    const float* dn  = (const float*)d_in[4];
    const float* npz = (const float*)d_in[5];
    const float* nnz = (const float*)d_in[6];
    float* out = (float*)d_out;

    uint* scal = (uint*)d_ws;
    ushort* xq = (ushort*)((char*)d_ws + 256);
    ushort* wb = (ushort*)((char*)d_ws + 256 + (size_t)B_ * IN_ * 2);
    if (ws_size < 256 + (size_t)B_ * IN_ * 2 + (size_t)OUT_ * IN_ * 2) return;

    k_init<<<1, 64, 0, stream>>>(scal);
    k_maxabs<<<2048, 256, 0, stream>>>((const f32x4*)x, B_ * IN_ / 4, scal);
    k_quantx<<<2048, 256, 0, stream>>>((const f32x4*)x, (uint4v*)xq, B_ * IN_ / 8, scal);
    k_weff<<<2048, 256, 0, stream>>>((const f32x4*)W, (const f32x4*)dp, (const f32x4*)dn,
                                     (const f32x4*)npz, (const f32x4*)nnz,
                                     (uint2v*)wb, OUT_ * IN_ / 4);
    k_gemm<1><<<256, 512, 0, stream>>>(xq, wb, scal, bias, out);
    k_gemm<2><<<256, 512, 0, stream>>>(xq, wb, scal, bias, out);
}